// Round 11
// baseline (870.317 us; speedup 1.0000x reference)
//
#include <hip/hip_runtime.h>
#include <hip/hip_bf16.h>

using bf16 = __hip_bfloat16;
typedef __attribute__((ext_vector_type(16))) float f32x16;
typedef __attribute__((ext_vector_type(4)))  int   i32x4;
typedef __attribute__((ext_vector_type(8)))  int   i32x8;

#define DEVINL __device__ __forceinline__

// activations stored x16 (dequant 2^-4 -> scale byte 0x7B)
// weights    stored x64 (dequant 2^-6 -> scale byte 0x79)
#define ASCALE 16.0f
#define WSCALE 64.0f
#define SCALE_A_DW 0x7B7B7B7B
#define SCALE_B_DW 0x79797979

DEVINL unsigned char f2fp8(float x) {   // e4m3 (OCP), saturating
    return (unsigned char)(__builtin_amdgcn_cvt_pk_fp8_f32(x, x, 0, 0) & 0xff);
}

DEVINL void gload_lds16(const void* g, void* l) {
    __builtin_amdgcn_global_load_lds(
        (const __attribute__((address_space(1))) void*)g,
        (__attribute__((address_space(3))) void*)l,
        16, 0, 0);
}

// ---------------------------------------------------------------------------
__global__ void init_acc(double* acc) {
    if (threadIdx.x < 2) acc[threadIdx.x] = 0.0;
}

// ---------------------------------------------------------------------------
// transpose + cast + scale: W[K][N] f32 -> WT[g(N)][K] fp8 (x64)
// interleave=1 (for W2): out row g(c) = c<1024 ? 2c : 2(c-1024)+1, so that
// WT rows alternate mu-col / lv-col -- GEMM2 epilogue pairs them by lane^1.
// ---------------------------------------------------------------------------
__global__ void transpose_cast_fp8(const float* __restrict__ W,
                                   unsigned char* __restrict__ WT,
                                   int K, int N, int interleave) {
    __shared__ float tile[32][33];
    int n0 = blockIdx.x * 32, k0 = blockIdx.y * 32;
    int tx = threadIdx.x, ty0 = threadIdx.y;   // block 32 x 8
#pragma unroll
    for (int i = 0; i < 4; ++i) {
        int ty = ty0 + i * 8;
        tile[ty][tx] = W[(size_t)(k0 + ty) * N + n0 + tx];
    }
    __syncthreads();
#pragma unroll
    for (int i = 0; i < 4; ++i) {
        int ty = ty0 + i * 8;
        int src = n0 + ty;
        int orow = interleave ? ((src < 1024) ? 2 * src : 2 * (src - 1024) + 1)
                              : src;
        WT[(size_t)orow * K + k0 + tx] = f2fp8(tile[tx][ty] * WSCALE);
    }
}

// ---------------------------------------------------------------------------
// gather sampled rows (rows <8192 come from hidden flat) -> fp8 x16
// ---------------------------------------------------------------------------
__global__ void gather_cast(const float* __restrict__ hidden,
                            const float* __restrict__ memory,
                            const int* __restrict__ idx,
                            unsigned char* __restrict__ samples8) {
    int s = blockIdx.x;
    int r = idx[s];
    const float* src = (r < 8192) ? hidden + (size_t)r * 4096
                                  : memory + (size_t)r * 4096;
    unsigned char* d8 = samples8 + (size_t)s * 4096;
#pragma unroll
    for (int c = threadIdx.x * 4; c < 4096; c += 1024) {
        float4 v = *(const float4*)(src + c);
        int w = __builtin_amdgcn_cvt_pk_fp8_f32(v.x * ASCALE, v.y * ASCALE, 0, 0);
        w = __builtin_amdgcn_cvt_pk_fp8_f32(v.z * ASCALE, v.w * ASCALE, w, 1);
        *(unsigned int*)(d8 + c) = (unsigned int)w;
    }
}

// ---------------------------------------------------------------------------
// MX-fp8 GEMM: 128x128 tile, BK=64 B, **2 waves** (128 thr), wave tile
// 128x64 (both waves share the A rows -> FLOP/LDS-byte 43->51). LDS 32 KiB
// double-buffered -> 4 blocks/CU (R10's drain-hiding occupancy). acc =
// f32x16[4][2] = 128 f32; <=1 A-frag + 2 B-frags live (~200 regs, cap 256).
// Swizzle skb^(row&3) over 4x16B slots, both sides (2-way = free, m136).
// C/D 32x32 map [m101]: col=lane&31, row=(reg&3)+8*(reg>>2)+4*(lane>>5).
// EPI: 0 = gelu(exact)->fp8 x16
//      2 = fused reparam: interleaved (mu,lv) cols -> z fp8 + KL partials
//      3 = recon MSE vs deq(s8)
// ---------------------------------------------------------------------------
template <int EPI>
__global__ __launch_bounds__(128, 2)
void gemm128f8(const unsigned char* __restrict__ A,
               const unsigned char* __restrict__ BT,
               const float* __restrict__ bias, void* __restrict__ Cout,
               const unsigned char* __restrict__ S,
               const float* __restrict__ EPS, double* __restrict__ accum,
               int M, int N, int K, int MT) {
    __shared__ __align__(16) unsigned char lds[2][2][128 * 64];

    const int tid  = threadIdx.x;
    const int lane = tid & 63;
    const int wc   = tid >> 6;      // 0..1 : N-half owned by this wave

    // XCD-aware bijective chunked decode (gridDim.x % 8 == 0 here)
    const int nwg  = gridDim.x;
    const int cpx  = nwg >> 3;
    const int work = (blockIdx.x & 7) * cpx + (blockIdx.x >> 3);
    const int ntile = work / MT;
    const int mtile = work - ntile * MT;
    const int m0 = mtile * 128;
    const int n0 = ntile * 128;

    const int nk = K >> 6;          // # K-steps of 64 bytes

    const int srow = tid >> 2;      // 0..31
    const int skb  = tid & 3;       // 16B slot 0..3

    auto stage = [&](int buf, int kt) {
        const size_t kcol = (size_t)kt * 64;
#pragma unroll
        for (int mat = 0; mat < 2; ++mat) {
            const unsigned char* G = mat ? BT : A;
            const int base0 = mat ? n0 : m0;
#pragma unroll
            for (int j = 0; j < 4; ++j) {
                int row = j * 32 + srow;
                int sg  = skb ^ (row & 3);        // inverse-swizzled source
                gload_lds16(G + (size_t)(base0 + row) * K + kcol + (size_t)sg * 16,
                            &lds[buf][mat][row * 64 + skb * 16]);  // linear dest
            }
        }
    };

    const int g32 = (lane >> 5);       // k-chunk group (0..1)
    const int l31 = lane & 31;
    auto rdfrag = [&](const unsigned char* base, int row) -> i32x8 {
        const unsigned char* rp = base + row * 64;
        int r3 = row & 3;
        int s0 = g32 * 2;
        i32x4 lo = *(const i32x4*)(rp + (((s0    ) ^ r3) << 4));
        i32x4 hi = *(const i32x4*)(rp + (((s0 + 1) ^ r3) << 4));
        return __builtin_shufflevector(lo, hi, 0, 1, 2, 3, 4, 5, 6, 7);
    };

    f32x16 acc[4][2] = {};

    stage(0, 0);
    __syncthreads();
    int cur = 0;
    for (int t = 0; t < nk; ++t) {
        if (t + 1 < nk) stage(cur ^ 1, t + 1);
        i32x8 b0 = rdfrag(lds[cur][1], wc * 64 +  0 + l31);
        i32x8 b1 = rdfrag(lds[cur][1], wc * 64 + 32 + l31);
#pragma unroll
        for (int mi = 0; mi < 4; ++mi) {
            i32x8 a = rdfrag(lds[cur][0], mi * 32 + l31);
            acc[mi][0] = __builtin_amdgcn_mfma_scale_f32_32x32x64_f8f6f4(
                a, b0, acc[mi][0], 0, 0, 0, SCALE_A_DW, 0, SCALE_B_DW);
            acc[mi][1] = __builtin_amdgcn_mfma_scale_f32_32x32x64_f8f6f4(
                a, b1, acc[mi][1], 0, 0, 0, SCALE_A_DW, 0, SCALE_B_DW);
        }
        __syncthreads();
        cur ^= 1;
    }

    // epilogue: 32x32 C/D map col=lane&31, row=(reg&3)+8*(reg>>2)+4*(lane>>5)
    float lsum = 0.f;
#pragma unroll
    for (int mi = 0; mi < 4; ++mi) {
#pragma unroll
        for (int nj = 0; nj < 2; ++nj) {
            int colg = n0 + wc * 64 + nj * 32 + l31;
            float bv;
            if (EPI == 2)
                bv = (colg & 1) ? bias[1024 + (colg >> 1)] : bias[colg >> 1];
            else
                bv = bias[colg];
#pragma unroll
            for (int reg = 0; reg < 16; ++reg) {
                int row = m0 + mi * 32 + (reg & 3) + 8 * (reg >> 2) + 4 * g32;
                float v = acc[mi][nj][reg] + bv;
                if (EPI == 0) {
                    float ge = 0.5f * v * (1.f + erff(v * 0.70710678118f));
                    ((unsigned char*)Cout)[(size_t)row * N + colg] =
                        f2fp8(ge * ASCALE);
                } else if (EPI == 2) {
                    float other = __shfl_xor(v, 1);
                    if ((lane & 1) == 0) {
                        float mu = v, lv = other;
                        float el = expf(lv);
                        size_t zi = (size_t)row * 1024 + (colg >> 1);
                        float zz = mu + sqrtf(el) * EPS[zi];
                        ((unsigned char*)Cout)[zi] = f2fp8(zz * ASCALE);
                        lsum += 1.f + lv - mu * mu - el;
                    }
                } else {
                    unsigned int sb = S[(size_t)row * N + colg];
                    float sv = __builtin_amdgcn_cvt_f32_fp8(sb, 0) * (1.0f / ASCALE);
                    float d = v - sv;
                    lsum += d * d;
                }
            }
        }
    }

    if (EPI == 2 || EPI == 3) {
        __shared__ float red[2];
        float v = lsum;
#pragma unroll
        for (int o = 32; o > 0; o >>= 1) v += __shfl_down(v, o);
        if (lane == 0) red[wc] = v;
        __syncthreads();
        if (tid == 0) {
            double t = (double)red[0] + (double)red[1];
            atomicAdd(accum + (EPI == 2 ? 1 : 0), t);
        }
    }
}

// ---------------------------------------------------------------------------
__global__ void finalize_kernel(const double* __restrict__ acc,
                                float* __restrict__ out) {
    if (threadIdx.x == 0)
        out[0] = (float)(acc[0] * (1.0 / (16384.0 * 4096.0)) - 0.0005 * acc[1]);
}

// ---------------------------------------------------------------------------
extern "C" void kernel_launch(void* const* d_in, const int* in_sizes, int n_in,
                              void* d_out, int out_size, void* d_ws, size_t ws_size,
                              hipStream_t stream) {
    const float* hidden = (const float*)d_in[0];
    const float* memory = (const float*)d_in[1];
    const int*   idx    = (const int*)d_in[2];
    const float* eps    = (const float*)d_in[3];
    const float* W1     = (const float*)d_in[4];
    const float* b1     = (const float*)d_in[5];
    const float* W2     = (const float*)d_in[6];
    const float* b2     = (const float*)d_in[7];
    const float* Wd1    = (const float*)d_in[8];
    const float* bd1    = (const float*)d_in[9];
    const float* Wd2    = (const float*)d_in[10];
    const float* bd2    = (const float*)d_in[11];

    char* ws = (char*)d_ws;
    double* acc            = (double*)ws;                            // 256 B
    unsigned char* s8      = (unsigned char*)(ws + 256);             // 67 MB
    unsigned char* h8      = s8   + (size_t)16384 * 4096;            // 33.6 MB
    unsigned char* z8      = h8   + (size_t)16384 * 2048;            // 16.8 MB
    unsigned char* hd8     = z8   + (size_t)16384 * 1024;            // 33.6 MB
    unsigned char* W1T     = hd8  + (size_t)16384 * 2048;
    unsigned char* W2T     = W1T  + (size_t)2048 * 4096;
    unsigned char* Wd1T    = W2T  + (size_t)2048 * 2048;
    unsigned char* Wd2T    = Wd1T + (size_t)2048 * 1024;

    init_acc<<<1, 64, 0, stream>>>(acc);

    dim3 tb(32, 8);
    transpose_cast_fp8<<<dim3(64, 128), tb, 0, stream>>>(W1, W1T, 4096, 2048, 0);
    transpose_cast_fp8<<<dim3(64, 64),  tb, 0, stream>>>(W2, W2T, 2048, 2048, 1);
    transpose_cast_fp8<<<dim3(64, 32),  tb, 0, stream>>>(Wd1, Wd1T, 1024, 2048, 0);
    transpose_cast_fp8<<<dim3(128, 64), tb, 0, stream>>>(Wd2, Wd2T, 2048, 4096, 0);

    gather_cast<<<16384, 256, 0, stream>>>(hidden, memory, idx, s8);

    // h = gelu(samples @ W1 + b1)          M=16384 N=2048 K=4096
    gemm128f8<0><<<2048, 128, 0, stream>>>(s8, W1T, b1, h8, nullptr, nullptr,
                                           nullptr, 16384, 2048, 4096, 128);
    // enc (interleaved) -> fused reparam: z fp8 + KL partials   K=2048
    gemm128f8<2><<<2048, 128, 0, stream>>>(h8, W2T, b2, z8, nullptr, eps,
                                           acc, 16384, 2048, 2048, 128);
    // hd = gelu(z @ Wd1 + bd1)             K=1024
    gemm128f8<0><<<2048, 128, 0, stream>>>(z8, Wd1T, bd1, hd8, nullptr, nullptr,
                                           nullptr, 16384, 2048, 1024, 128);
    // rec = hd @ Wd2 + bd2 ; fused recon MSE vs deq(s8)   N=4096 K=2048
    gemm128f8<3><<<4096, 128, 0, stream>>>(hd8, Wd2T, bd2, nullptr, s8,
                                           nullptr, acc, 16384, 4096, 2048, 128);

    finalize_kernel<<<1, 64, 0, stream>>>(acc, (float*)d_out);
}

// Round 12
// 708.850 us; speedup vs baseline: 1.2278x; 1.2278x over previous
//
#include <hip/hip_runtime.h>
#include <hip/hip_bf16.h>

using bf16 = __hip_bfloat16;
typedef __attribute__((ext_vector_type(16))) float f32x16;
typedef __attribute__((ext_vector_type(4)))  int   i32x4;
typedef __attribute__((ext_vector_type(8)))  int   i32x8;

#define DEVINL __device__ __forceinline__

// activations stored x16 (dequant 2^-4 -> scale byte 0x7B)
// weights    stored x64 (dequant 2^-6 -> scale byte 0x79)
#define ASCALE 16.0f
#define WSCALE 64.0f
#define SCALE_A_DW 0x7B7B7B7B
#define SCALE_B_DW 0x79797979

DEVINL unsigned char f2fp8(float x) {   // e4m3 (OCP), saturating
    return (unsigned char)(__builtin_amdgcn_cvt_pk_fp8_f32(x, x, 0, 0) & 0xff);
}

DEVINL void gload_lds16(const void* g, void* l) {
    __builtin_amdgcn_global_load_lds(
        (const __attribute__((address_space(1))) void*)g,
        (__attribute__((address_space(3))) void*)l,
        16, 0, 0);
}

// ---------------------------------------------------------------------------
__global__ void init_acc(double* acc) {
    if (threadIdx.x < 2) acc[threadIdx.x] = 0.0;
}

// ---------------------------------------------------------------------------
// transpose + cast + scale: W[K][N] f32 -> WT[g(N)][K] fp8 (x64)
// interleave=1 (for W2): out row g(c) = c<1024 ? 2c : 2(c-1024)+1, so that
// WT rows alternate mu-col / lv-col -- GEMM2 epilogue pairs them by lane^1.
// ---------------------------------------------------------------------------
__global__ void transpose_cast_fp8(const float* __restrict__ W,
                                   unsigned char* __restrict__ WT,
                                   int K, int N, int interleave) {
    __shared__ float tile[32][33];
    int n0 = blockIdx.x * 32, k0 = blockIdx.y * 32;
    int tx = threadIdx.x, ty0 = threadIdx.y;   // block 32 x 8
#pragma unroll
    for (int i = 0; i < 4; ++i) {
        int ty = ty0 + i * 8;
        tile[ty][tx] = W[(size_t)(k0 + ty) * N + n0 + tx];
    }
    __syncthreads();
#pragma unroll
    for (int i = 0; i < 4; ++i) {
        int ty = ty0 + i * 8;
        int src = n0 + ty;
        int orow = interleave ? ((src < 1024) ? 2 * src : 2 * (src - 1024) + 1)
                              : src;
        WT[(size_t)orow * K + k0 + tx] = f2fp8(tile[tx][ty] * WSCALE);
    }
}

// ---------------------------------------------------------------------------
// gather sampled rows (rows <8192 come from hidden flat) -> fp8 x16
// ---------------------------------------------------------------------------
__global__ void gather_cast(const float* __restrict__ hidden,
                            const float* __restrict__ memory,
                            const int* __restrict__ idx,
                            unsigned char* __restrict__ samples8) {
    int s = blockIdx.x;
    int r = idx[s];
    const float* src = (r < 8192) ? hidden + (size_t)r * 4096
                                  : memory + (size_t)r * 4096;
    unsigned char* d8 = samples8 + (size_t)s * 4096;
#pragma unroll
    for (int c = threadIdx.x * 4; c < 4096; c += 1024) {
        float4 v = *(const float4*)(src + c);
        int w = __builtin_amdgcn_cvt_pk_fp8_f32(v.x * ASCALE, v.y * ASCALE, 0, 0);
        w = __builtin_amdgcn_cvt_pk_fp8_f32(v.z * ASCALE, v.w * ASCALE, w, 1);
        *(unsigned int*)(d8 + c) = (unsigned int)w;
    }
}

// ---------------------------------------------------------------------------
// MX-fp8 GEMM (R10 geometry, register-lean): 128x128 tile, BK=64 B, 4 waves
// (2x2), double-buffered LDS 32 KiB -> 4 blocks/CU (16 waves/CU -- the
// proven drain-hiding occupancy). Lean K-loop: {b0,b1; for mi: a -> 2 MFMA}
// keeps peak live regs ~112 (<128 cap from launch_bounds(256,4)).
// Swizzle skb^(row&3) over 4x16B slots, both sides (2-way = free, m136).
// C/D 32x32 map [m101]: col=lane&31, row=(reg&3)+8*(reg>>2)+4*(lane>>5).
// EPI: 0 = gelu(exact)->fp8 x16
//      2 = fused reparam: interleaved (mu,lv) cols -> z fp8 + KL partials
//      3 = recon MSE vs deq(s8)
// ---------------------------------------------------------------------------
template <int EPI>
__global__ __launch_bounds__(256, 4)
void gemm128f8(const unsigned char* __restrict__ A,
               const unsigned char* __restrict__ BT,
               const float* __restrict__ bias, void* __restrict__ Cout,
               const unsigned char* __restrict__ S,
               const float* __restrict__ EPS, double* __restrict__ accum,
               int M, int N, int K, int MT) {
    __shared__ __align__(16) unsigned char lds[2][2][128 * 64];

    const int tid  = threadIdx.x;
    const int lane = tid & 63;
    const int wave = tid >> 6;      // 0..3
    const int wr   = wave >> 1;     // 0..1
    const int wc   = wave & 1;      // 0..1

    // XCD-aware bijective chunked decode (gridDim.x % 8 == 0 here)
    const int nwg  = gridDim.x;
    const int cpx  = nwg >> 3;
    const int work = (blockIdx.x & 7) * cpx + (blockIdx.x >> 3);
    const int ntile = work / MT;
    const int mtile = work - ntile * MT;
    const int m0 = mtile * 128;
    const int n0 = ntile * 128;

    const int nk = K >> 6;          // # K-steps of 64 bytes

    const int srow = tid >> 2;      // 0..63
    const int skb  = tid & 3;       // 16B slot 0..3

    auto stage = [&](int buf, int kt) {
        const size_t kcol = (size_t)kt * 64;
#pragma unroll
        for (int mat = 0; mat < 2; ++mat) {
            const unsigned char* G = mat ? BT : A;
            const int base0 = mat ? n0 : m0;
#pragma unroll
            for (int j = 0; j < 2; ++j) {
                int row = j * 64 + srow;
                int sg  = skb ^ (row & 3);        // inverse-swizzled source
                gload_lds16(G + (size_t)(base0 + row) * K + kcol + (size_t)sg * 16,
                            &lds[buf][mat][row * 64 + skb * 16]);  // linear dest
            }
        }
    };

    const int g32 = (lane >> 5);       // k-chunk group (0..1)
    const int l31 = lane & 31;
    auto rdfrag = [&](const unsigned char* base, int row) -> i32x8 {
        const unsigned char* rp = base + row * 64;
        int r3 = row & 3;
        int s0 = g32 * 2;
        i32x4 lo = *(const i32x4*)(rp + (((s0    ) ^ r3) << 4));
        i32x4 hi = *(const i32x4*)(rp + (((s0 + 1) ^ r3) << 4));
        return __builtin_shufflevector(lo, hi, 0, 1, 2, 3, 4, 5, 6, 7);
    };

    f32x16 acc[2][2] = {};

    stage(0, 0);
    __syncthreads();
    int cur = 0;
    for (int t = 0; t < nk; ++t) {
        if (t + 1 < nk) stage(cur ^ 1, t + 1);
        i32x8 b0 = rdfrag(lds[cur][1], wc * 64 +  0 + l31);
        i32x8 b1 = rdfrag(lds[cur][1], wc * 64 + 32 + l31);
#pragma unroll
        for (int mi = 0; mi < 2; ++mi) {
            i32x8 a = rdfrag(lds[cur][0], wr * 64 + mi * 32 + l31);
            __builtin_amdgcn_s_setprio(1);
            acc[mi][0] = __builtin_amdgcn_mfma_scale_f32_32x32x64_f8f6f4(
                a, b0, acc[mi][0], 0, 0, 0, SCALE_A_DW, 0, SCALE_B_DW);
            acc[mi][1] = __builtin_amdgcn_mfma_scale_f32_32x32x64_f8f6f4(
                a, b1, acc[mi][1], 0, 0, 0, SCALE_A_DW, 0, SCALE_B_DW);
            __builtin_amdgcn_s_setprio(0);
        }
        __syncthreads();
        cur ^= 1;
    }

    // epilogue: 32x32 C/D map col=lane&31, row=(reg&3)+8*(reg>>2)+4*(lane>>5)
    float lsum = 0.f;
#pragma unroll
    for (int mi = 0; mi < 2; ++mi) {
#pragma unroll
        for (int nj = 0; nj < 2; ++nj) {
            int colg = n0 + wc * 64 + nj * 32 + l31;
            float bv;
            if (EPI == 2)
                bv = (colg & 1) ? bias[1024 + (colg >> 1)] : bias[colg >> 1];
            else
                bv = bias[colg];
#pragma unroll
            for (int reg = 0; reg < 16; ++reg) {
                int row = m0 + wr * 64 + mi * 32 +
                          (reg & 3) + 8 * (reg >> 2) + 4 * g32;
                float v = acc[mi][nj][reg] + bv;
                if (EPI == 0) {
                    float ge = 0.5f * v * (1.f + erff(v * 0.70710678118f));
                    ((unsigned char*)Cout)[(size_t)row * N + colg] =
                        f2fp8(ge * ASCALE);
                } else if (EPI == 2) {
                    float other = __shfl_xor(v, 1);
                    if ((lane & 1) == 0) {
                        float mu = v, lv = other;
                        float el = expf(lv);
                        size_t zi = (size_t)row * 1024 + (colg >> 1);
                        float zz = mu + sqrtf(el) * EPS[zi];
                        ((unsigned char*)Cout)[zi] = f2fp8(zz * ASCALE);
                        lsum += 1.f + lv - mu * mu - el;
                    }
                } else {
                    unsigned int sb = S[(size_t)row * N + colg];
                    float sv = __builtin_amdgcn_cvt_f32_fp8(sb, 0) * (1.0f / ASCALE);
                    float d = v - sv;
                    lsum += d * d;
                }
            }
        }
    }

    if (EPI == 2 || EPI == 3) {
        __shared__ float red[4];
        float v = lsum;
#pragma unroll
        for (int o = 32; o > 0; o >>= 1) v += __shfl_down(v, o);
        if (lane == 0) red[wave] = v;
        __syncthreads();
        if (tid == 0) {
            double t = (double)red[0] + (double)red[1] +
                       (double)red[2] + (double)red[3];
            atomicAdd(accum + (EPI == 2 ? 1 : 0), t);
        }
    }
}

// ---------------------------------------------------------------------------
__global__ void finalize_kernel(const double* __restrict__ acc,
                                float* __restrict__ out) {
    if (threadIdx.x == 0)
        out[0] = (float)(acc[0] * (1.0 / (16384.0 * 4096.0)) - 0.0005 * acc[1]);
}

// ---------------------------------------------------------------------------
extern "C" void kernel_launch(void* const* d_in, const int* in_sizes, int n_in,
                              void* d_out, int out_size, void* d_ws, size_t ws_size,
                              hipStream_t stream) {
    const float* hidden = (const float*)d_in[0];
    const float* memory = (const float*)d_in[1];
    const int*   idx    = (const int*)d_in[2];
    const float* eps    = (const float*)d_in[3];
    const float* W1     = (const float*)d_in[4];
    const float* b1     = (const float*)d_in[5];
    const float* W2     = (const float*)d_in[6];
    const float* b2     = (const float*)d_in[7];
    const float* Wd1    = (const float*)d_in[8];
    const float* bd1    = (const float*)d_in[9];
    const float* Wd2    = (const float*)d_in[10];
    const float* bd2    = (const float*)d_in[11];

    char* ws = (char*)d_ws;
    double* acc            = (double*)ws;                            // 256 B
    unsigned char* s8      = (unsigned char*)(ws + 256);             // 67 MB
    unsigned char* h8      = s8   + (size_t)16384 * 4096;            // 33.6 MB
    unsigned char* z8      = h8   + (size_t)16384 * 2048;            // 16.8 MB
    unsigned char* hd8     = z8   + (size_t)16384 * 1024;            // 33.6 MB
    unsigned char* W1T     = hd8  + (size_t)16384 * 2048;
    unsigned char* W2T     = W1T  + (size_t)2048 * 4096;
    unsigned char* Wd1T    = W2T  + (size_t)2048 * 2048;
    unsigned char* Wd2T    = Wd1T + (size_t)2048 * 1024;

    init_acc<<<1, 64, 0, stream>>>(acc);

    dim3 tb(32, 8);
    transpose_cast_fp8<<<dim3(64, 128), tb, 0, stream>>>(W1, W1T, 4096, 2048, 0);
    transpose_cast_fp8<<<dim3(64, 64),  tb, 0, stream>>>(W2, W2T, 2048, 2048, 1);
    transpose_cast_fp8<<<dim3(64, 32),  tb, 0, stream>>>(Wd1, Wd1T, 1024, 2048, 0);
    transpose_cast_fp8<<<dim3(128, 64), tb, 0, stream>>>(Wd2, Wd2T, 2048, 4096, 0);

    gather_cast<<<16384, 256, 0, stream>>>(hidden, memory, idx, s8);

    // h = gelu(samples @ W1 + b1)          M=16384 N=2048 K=4096
    gemm128f8<0><<<2048, 256, 0, stream>>>(s8, W1T, b1, h8, nullptr, nullptr,
                                           nullptr, 16384, 2048, 4096, 128);
    // enc (interleaved) -> fused reparam: z fp8 + KL partials   K=2048
    gemm128f8<2><<<2048, 256, 0, stream>>>(h8, W2T, b2, z8, nullptr, eps,
                                           acc, 16384, 2048, 2048, 128);
    // hd = gelu(z @ Wd1 + bd1)             K=1024
    gemm128f8<0><<<2048, 256, 0, stream>>>(z8, Wd1T, bd1, hd8, nullptr, nullptr,
                                           nullptr, 16384, 2048, 1024, 128);
    // rec = hd @ Wd2 + bd2 ; fused recon MSE vs deq(s8)   N=4096 K=2048
    gemm128f8<3><<<4096, 256, 0, stream>>>(hd8, Wd2T, bd2, nullptr, s8,
                                           nullptr, acc, 16384, 4096, 2048, 128);

    finalize_kernel<<<1, 64, 0, stream>>>(acc, (float*)d_out);
}

// Round 13
// 680.946 us; speedup vs baseline: 1.2781x; 1.0410x over previous
//
#include <hip/hip_runtime.h>
#include <hip/hip_bf16.h>

using bf16 = __hip_bfloat16;
typedef __attribute__((ext_vector_type(16))) float f32x16;
typedef __attribute__((ext_vector_type(4)))  int   i32x4;
typedef __attribute__((ext_vector_type(8)))  int   i32x8;

#define DEVINL __device__ __forceinline__

// activations stored x16 (dequant 2^-4 -> scale byte 0x7B)
// weights    stored x64 (dequant 2^-6 -> scale byte 0x79)
#define ASCALE 16.0f
#define WSCALE 64.0f
#define SCALE_A_DW 0x7B7B7B7B
#define SCALE_B_DW 0x79797979

DEVINL unsigned char f2fp8(float x) {   // e4m3 (OCP), saturating
    return (unsigned char)(__builtin_amdgcn_cvt_pk_fp8_f32(x, x, 0, 0) & 0xff);
}

DEVINL void gload_lds16(const void* g, void* l) {
    __builtin_amdgcn_global_load_lds(
        (const __attribute__((address_space(1))) void*)g,
        (__attribute__((address_space(3))) void*)l,
        16, 0, 0);
}

// ---------------------------------------------------------------------------
// unified prep kernel (one launch, independent block ranges run concurrently)
//   blocks [0, 16384)            : gather+cast one sample row -> fp8 x16
//   blocks [16384, +8192)        : transpose W1  (64 x 128 tiles)
//   blocks [24576, +4096)        : transpose W2  (64 x 64, mu/lv interleave)
//   blocks [28672, +2048)        : transpose Wd1 (64 x 32)
//   blocks [30720, +8192)        : transpose Wd2 (128 x 64)
//   block 0, tids 0-1            : zero the loss accumulators
// ---------------------------------------------------------------------------
__global__ __launch_bounds__(256)
void prep_kernel(const float* __restrict__ hidden,
                 const float* __restrict__ memory,
                 const int* __restrict__ idx,
                 unsigned char* __restrict__ s8,
                 const float* __restrict__ W1, unsigned char* __restrict__ W1T,
                 const float* __restrict__ W2, unsigned char* __restrict__ W2T,
                 const float* __restrict__ Wd1, unsigned char* __restrict__ Wd1T,
                 const float* __restrict__ Wd2, unsigned char* __restrict__ Wd2T,
                 double* __restrict__ acc) {
    int b = blockIdx.x;
    if (b == 0 && threadIdx.x < 2) acc[threadIdx.x] = 0.0;

    if (b < 16384) {
        // ---- gather + cast ----
        int r = idx[b];
        const float* src = (r < 8192) ? hidden + (size_t)r * 4096
                                      : memory + (size_t)r * 4096;
        unsigned char* d8 = s8 + (size_t)b * 4096;
#pragma unroll
        for (int c = threadIdx.x * 4; c < 4096; c += 1024) {
            float4 v = *(const float4*)(src + c);
            int w = __builtin_amdgcn_cvt_pk_fp8_f32(v.x * ASCALE, v.y * ASCALE, 0, 0);
            w = __builtin_amdgcn_cvt_pk_fp8_f32(v.z * ASCALE, v.w * ASCALE, w, 1);
            *(unsigned int*)(d8 + c) = (unsigned int)w;
        }
        return;
    }

    // ---- transpose tasks: W[K][N] f32 -> WT[g(N)][K] fp8 (x64) ----
    const float* W; unsigned char* WT; int K, N, NB, interleave = 0, t;
    if (b < 24576)      { t = b - 16384; W = W1;  WT = W1T;  K = 4096; N = 2048; NB = 64; }
    else if (b < 28672) { t = b - 24576; W = W2;  WT = W2T;  K = 2048; N = 2048; NB = 64; interleave = 1; }
    else if (b < 30720) { t = b - 28672; W = Wd1; WT = Wd1T; K = 1024; N = 2048; NB = 64; }
    else                { t = b - 30720; W = Wd2; WT = Wd2T; K = 2048; N = 4096; NB = 128; }

    __shared__ float tile[32][33];
    int n0 = (t % NB) * 32, k0 = (t / NB) * 32;
    int tx = threadIdx.x & 31, ty0 = threadIdx.x >> 5;   // 32 x 8
#pragma unroll
    for (int i = 0; i < 4; ++i) {
        int ty = ty0 + i * 8;
        tile[ty][tx] = W[(size_t)(k0 + ty) * N + n0 + tx];
    }
    __syncthreads();
#pragma unroll
    for (int i = 0; i < 4; ++i) {
        int ty = ty0 + i * 8;
        int src = n0 + ty;
        int orow = interleave ? ((src < 1024) ? 2 * src : 2 * (src - 1024) + 1)
                              : src;
        WT[(size_t)orow * K + k0 + tx] = f2fp8(tile[tx][ty] * WSCALE);
    }
}

// ---------------------------------------------------------------------------
// MX-fp8 GEMM (R10 structure verbatim -- the measured optimum):
// 128x128 tile, BK=64 B, 4 waves (2x2), double-buffered LDS 32 KiB ->
// 4 blocks/CU (16 waves/CU). Swizzle skb^(row&3), both sides (2-way = free).
// C/D 32x32 map [m101]: col=lane&31, row=(reg&3)+8*(reg>>2)+4*(lane>>5).
// EPI: 0 = gelu(exact)->fp8 x16
//      2 = fused reparam: interleaved (mu,lv) cols -> z fp8 + KL partials
//      3 = recon MSE vs deq(s8)
// ---------------------------------------------------------------------------
template <int EPI>
__global__ __launch_bounds__(256, 4)
void gemm128f8(const unsigned char* __restrict__ A,
               const unsigned char* __restrict__ BT,
               const float* __restrict__ bias, void* __restrict__ Cout,
               const unsigned char* __restrict__ S,
               const float* __restrict__ EPS, double* __restrict__ accum,
               int M, int N, int K, int MT) {
    __shared__ __align__(16) unsigned char lds[2][2][128 * 64];

    const int tid  = threadIdx.x;
    const int lane = tid & 63;
    const int wave = tid >> 6;      // 0..3
    const int wr   = wave >> 1;     // 0..1
    const int wc   = wave & 1;      // 0..1

    // XCD-aware bijective chunked decode (gridDim.x % 8 == 0 here)
    const int nwg  = gridDim.x;
    const int cpx  = nwg >> 3;
    const int work = (blockIdx.x & 7) * cpx + (blockIdx.x >> 3);
    const int ntile = work / MT;
    const int mtile = work - ntile * MT;
    const int m0 = mtile * 128;
    const int n0 = ntile * 128;

    const int nk = K >> 6;          // # K-steps of 64 bytes

    const int srow = tid >> 2;      // 0..63
    const int skb  = tid & 3;       // 16B slot 0..3

    auto stage = [&](int buf, int kt) {
        const size_t kcol = (size_t)kt * 64;
#pragma unroll
        for (int mat = 0; mat < 2; ++mat) {
            const unsigned char* G = mat ? BT : A;
            const int base0 = mat ? n0 : m0;
#pragma unroll
            for (int j = 0; j < 2; ++j) {
                int row = j * 64 + srow;
                int sg  = skb ^ (row & 3);        // inverse-swizzled source
                gload_lds16(G + (size_t)(base0 + row) * K + kcol + (size_t)sg * 16,
                            &lds[buf][mat][row * 64 + skb * 16]);  // linear dest
            }
        }
    };

    const int g32 = (lane >> 5);       // k-chunk group (0..1)
    const int l31 = lane & 31;
    auto rdfrag = [&](const unsigned char* base, int row) -> i32x8 {
        const unsigned char* rp = base + row * 64;
        int r3 = row & 3;
        int s0 = g32 * 2;
        i32x4 lo = *(const i32x4*)(rp + (((s0    ) ^ r3) << 4));
        i32x4 hi = *(const i32x4*)(rp + (((s0 + 1) ^ r3) << 4));
        return __builtin_shufflevector(lo, hi, 0, 1, 2, 3, 4, 5, 6, 7);
    };

    f32x16 acc[2][2] = {};

    stage(0, 0);
    __syncthreads();
    int cur = 0;
    for (int t = 0; t < nk; ++t) {
        if (t + 1 < nk) stage(cur ^ 1, t + 1);
        i32x8 a0 = rdfrag(lds[cur][0], wr * 64 +  0 + l31);
        i32x8 a1 = rdfrag(lds[cur][0], wr * 64 + 32 + l31);
        i32x8 b0 = rdfrag(lds[cur][1], wc * 64 +  0 + l31);
        i32x8 b1 = rdfrag(lds[cur][1], wc * 64 + 32 + l31);
        acc[0][0] = __builtin_amdgcn_mfma_scale_f32_32x32x64_f8f6f4(
            a0, b0, acc[0][0], 0, 0, 0, SCALE_A_DW, 0, SCALE_B_DW);
        acc[0][1] = __builtin_amdgcn_mfma_scale_f32_32x32x64_f8f6f4(
            a0, b1, acc[0][1], 0, 0, 0, SCALE_A_DW, 0, SCALE_B_DW);
        acc[1][0] = __builtin_amdgcn_mfma_scale_f32_32x32x64_f8f6f4(
            a1, b0, acc[1][0], 0, 0, 0, SCALE_A_DW, 0, SCALE_B_DW);
        acc[1][1] = __builtin_amdgcn_mfma_scale_f32_32x32x64_f8f6f4(
            a1, b1, acc[1][1], 0, 0, 0, SCALE_A_DW, 0, SCALE_B_DW);
        __syncthreads();
        cur ^= 1;
    }

    // epilogue: 32x32 C/D map col=lane&31, row=(reg&3)+8*(reg>>2)+4*(lane>>5)
    float lsum = 0.f;
#pragma unroll
    for (int mi = 0; mi < 2; ++mi) {
#pragma unroll
        for (int nj = 0; nj < 2; ++nj) {
            int colg = n0 + wc * 64 + nj * 32 + l31;
            float bv;
            if (EPI == 2)
                bv = (colg & 1) ? bias[1024 + (colg >> 1)] : bias[colg >> 1];
            else
                bv = bias[colg];
#pragma unroll
            for (int reg = 0; reg < 16; ++reg) {
                int row = m0 + wr * 64 + mi * 32 +
                          (reg & 3) + 8 * (reg >> 2) + 4 * g32;
                float v = acc[mi][nj][reg] + bv;
                if (EPI == 0) {
                    float ge = 0.5f * v * (1.f + erff(v * 0.70710678118f));
                    ((unsigned char*)Cout)[(size_t)row * N + colg] =
                        f2fp8(ge * ASCALE);
                } else if (EPI == 2) {
                    float other = __shfl_xor(v, 1);
                    if ((lane & 1) == 0) {
                        float mu = v, lv = other;
                        float el = expf(lv);
                        size_t zi = (size_t)row * 1024 + (colg >> 1);
                        float zz = mu + sqrtf(el) * EPS[zi];
                        ((unsigned char*)Cout)[zi] = f2fp8(zz * ASCALE);
                        lsum += 1.f + lv - mu * mu - el;
                    }
                } else {
                    unsigned int sb = S[(size_t)row * N + colg];
                    float sv = __builtin_amdgcn_cvt_f32_fp8(sb, 0) * (1.0f / ASCALE);
                    float d = v - sv;
                    lsum += d * d;
                }
            }
        }
    }

    if (EPI == 2 || EPI == 3) {
        __shared__ float red[4];
        float v = lsum;
#pragma unroll
        for (int o = 32; o > 0; o >>= 1) v += __shfl_down(v, o);
        if (lane == 0) red[wave] = v;
        __syncthreads();
        if (tid == 0) {
            double t = (double)red[0] + (double)red[1] +
                       (double)red[2] + (double)red[3];
            atomicAdd(accum + (EPI == 2 ? 1 : 0), t);
        }
    }
}

// ---------------------------------------------------------------------------
__global__ void finalize_kernel(const double* __restrict__ acc,
                                float* __restrict__ out) {
    if (threadIdx.x == 0)
        out[0] = (float)(acc[0] * (1.0 / (16384.0 * 4096.0)) - 0.0005 * acc[1]);
}

// ---------------------------------------------------------------------------
extern "C" void kernel_launch(void* const* d_in, const int* in_sizes, int n_in,
                              void* d_out, int out_size, void* d_ws, size_t ws_size,
                              hipStream_t stream) {
    const float* hidden = (const float*)d_in[0];
    const float* memory = (const float*)d_in[1];
    const int*   idx    = (const int*)d_in[2];
    const float* eps    = (const float*)d_in[3];
    const float* W1     = (const float*)d_in[4];
    const float* b1     = (const float*)d_in[5];
    const float* W2     = (const float*)d_in[6];
    const float* b2     = (const float*)d_in[7];
    const float* Wd1    = (const float*)d_in[8];
    const float* bd1    = (const float*)d_in[9];
    const float* Wd2    = (const float*)d_in[10];
    const float* bd2    = (const float*)d_in[11];

    char* ws = (char*)d_ws;
    double* acc            = (double*)ws;                            // 256 B
    unsigned char* s8      = (unsigned char*)(ws + 256);             // 67 MB
    unsigned char* h8      = s8   + (size_t)16384 * 4096;            // 33.6 MB
    unsigned char* z8      = h8   + (size_t)16384 * 2048;            // 16.8 MB
    unsigned char* hd8     = z8   + (size_t)16384 * 1024;            // 33.6 MB
    unsigned char* W1T     = hd8  + (size_t)16384 * 2048;
    unsigned char* W2T     = W1T  + (size_t)2048 * 4096;
    unsigned char* Wd1T    = W2T  + (size_t)2048 * 2048;
    unsigned char* Wd2T    = Wd1T + (size_t)2048 * 1024;

    // one fused prep launch: gather + 4 transposes + acc zeroing
    prep_kernel<<<38912, 256, 0, stream>>>(hidden, memory, idx, s8,
                                           W1, W1T, W2, W2T,
                                           Wd1, Wd1T, Wd2, Wd2T, acc);

    // h = gelu(samples @ W1 + b1)          M=16384 N=2048 K=4096
    gemm128f8<0><<<2048, 256, 0, stream>>>(s8, W1T, b1, h8, nullptr, nullptr,
                                           nullptr, 16384, 2048, 4096, 128);
    // enc (interleaved) -> fused reparam: z fp8 + KL partials   K=2048
    gemm128f8<2><<<2048, 256, 0, stream>>>(h8, W2T, b2, z8, nullptr, eps,
                                           acc, 16384, 2048, 2048, 128);
    // hd = gelu(z @ Wd1 + bd1)             K=1024
    gemm128f8<0><<<2048, 256, 0, stream>>>(z8, Wd1T, bd1, hd8, nullptr, nullptr,
                                           nullptr, 16384, 2048, 1024, 128);
    // rec = hd @ Wd2 + bd2 ; fused recon MSE vs deq(s8)   N=4096 K=2048
    gemm128f8<3><<<4096, 256, 0, stream>>>(hd8, Wd2T, bd2, nullptr, s8,
                                           nullptr, acc, 16384, 4096, 2048, 128);

    finalize_kernel<<<1, 64, 0, stream>>>(acc, (float*)d_out);
}

// Round 14
// 676.444 us; speedup vs baseline: 1.2866x; 1.0067x over previous
//
#include <hip/hip_runtime.h>
#include <hip/hip_bf16.h>

using bf16 = __hip_bfloat16;
typedef __attribute__((ext_vector_type(16))) float f32x16;
typedef __attribute__((ext_vector_type(4)))  int   i32x4;
typedef __attribute__((ext_vector_type(8)))  int   i32x8;

#define DEVINL __device__ __forceinline__

// activations stored x16 (dequant 2^-4 -> scale byte 0x7B)
// weights    stored x64 (dequant 2^-6 -> scale byte 0x79)
#define ASCALE 16.0f
#define WSCALE 64.0f
#define SCALE_A_DW 0x7B7B7B7B
#define SCALE_B_DW 0x79797979

DEVINL unsigned char f2fp8(float x) {   // e4m3 (OCP), saturating
    return (unsigned char)(__builtin_amdgcn_cvt_pk_fp8_f32(x, x, 0, 0) & 0xff);
}

DEVINL void gload_lds16(const void* g, void* l) {
    __builtin_amdgcn_global_load_lds(
        (const __attribute__((address_space(1))) void*)g,
        (__attribute__((address_space(3))) void*)l,
        16, 0, 0);
}

// ---------------------------------------------------------------------------
// unified prep kernel (one launch, independent block ranges run concurrently)
//   blocks [0, 16384)            : gather+cast one sample row -> fp8 x16
//   blocks [16384, +8192)        : transpose W1  (64 x 128 tiles)
//   blocks [24576, +4096)        : transpose W2  (64 x 64, mu/lv interleave)
//   blocks [28672, +2048)        : transpose Wd1 (64 x 32)
//   blocks [30720, +8192)        : transpose Wd2 (128 x 64)
//   block 0, tids 0-1            : zero the loss accumulators
// ---------------------------------------------------------------------------
__global__ __launch_bounds__(256)
void prep_kernel(const float* __restrict__ hidden,
                 const float* __restrict__ memory,
                 const int* __restrict__ idx,
                 unsigned char* __restrict__ s8,
                 const float* __restrict__ W1, unsigned char* __restrict__ W1T,
                 const float* __restrict__ W2, unsigned char* __restrict__ W2T,
                 const float* __restrict__ Wd1, unsigned char* __restrict__ Wd1T,
                 const float* __restrict__ Wd2, unsigned char* __restrict__ Wd2T,
                 double* __restrict__ acc) {
    int b = blockIdx.x;
    if (b == 0 && threadIdx.x < 2) acc[threadIdx.x] = 0.0;

    if (b < 16384) {
        // ---- gather + cast ----
        int r = idx[b];
        const float* src = (r < 8192) ? hidden + (size_t)r * 4096
                                      : memory + (size_t)r * 4096;
        unsigned char* d8 = s8 + (size_t)b * 4096;
#pragma unroll
        for (int c = threadIdx.x * 4; c < 4096; c += 1024) {
            float4 v = *(const float4*)(src + c);
            int w = __builtin_amdgcn_cvt_pk_fp8_f32(v.x * ASCALE, v.y * ASCALE, 0, 0);
            w = __builtin_amdgcn_cvt_pk_fp8_f32(v.z * ASCALE, v.w * ASCALE, w, 1);
            *(unsigned int*)(d8 + c) = (unsigned int)w;
        }
        return;
    }

    // ---- transpose tasks: W[K][N] f32 -> WT[g(N)][K] fp8 (x64) ----
    const float* W; unsigned char* WT; int K, N, NB, interleave = 0, t;
    if (b < 24576)      { t = b - 16384; W = W1;  WT = W1T;  K = 4096; N = 2048; NB = 64; }
    else if (b < 28672) { t = b - 24576; W = W2;  WT = W2T;  K = 2048; N = 2048; NB = 64; interleave = 1; }
    else if (b < 30720) { t = b - 28672; W = Wd1; WT = Wd1T; K = 1024; N = 2048; NB = 64; }
    else                { t = b - 30720; W = Wd2; WT = Wd2T; K = 2048; N = 4096; NB = 128; }

    __shared__ float tile[32][33];
    int n0 = (t % NB) * 32, k0 = (t / NB) * 32;
    int tx = threadIdx.x & 31, ty0 = threadIdx.x >> 5;   // 32 x 8
#pragma unroll
    for (int i = 0; i < 4; ++i) {
        int ty = ty0 + i * 8;
        tile[ty][tx] = W[(size_t)(k0 + ty) * N + n0 + tx];
    }
    __syncthreads();
#pragma unroll
    for (int i = 0; i < 4; ++i) {
        int ty = ty0 + i * 8;
        int src = n0 + ty;
        int orow = interleave ? ((src < 1024) ? 2 * src : 2 * (src - 1024) + 1)
                              : src;
        WT[(size_t)orow * K + k0 + tx] = f2fp8(tile[tx][ty] * WSCALE);
    }
}

// ---------------------------------------------------------------------------
// MX-fp8 GEMM (R10/R13 structure; bank-bijective swizzle):
// 128x128 tile, BK=64 B, 4 waves (2x2), double-buffered LDS 32 KiB ->
// 4 blocks/CU (16 waves/CU). Swizzle slot ^= (row>>1)&3, both sides:
// 16B-chunk index = (row&1)*4 + slot^((row>>1)&3) is BIJECTIVE over
// row mod 8 -> each 8-lane b128 phase hits 8 distinct bank groups
// (the old (row&3) variant folded rows onto 4 groups = 2-way/phase).
// C/D 32x32 map [m101]: col=lane&31, row=(reg&3)+8*(reg>>2)+4*(lane>>5).
// EPI: 0 = gelu(exact)->fp8 x16
//      2 = fused reparam: interleaved (mu,lv) cols -> z fp8 + KL partials
//      3 = recon MSE vs deq(s8)
// ---------------------------------------------------------------------------
template <int EPI>
__global__ __launch_bounds__(256, 4)
void gemm128f8(const unsigned char* __restrict__ A,
               const unsigned char* __restrict__ BT,
               const float* __restrict__ bias, void* __restrict__ Cout,
               const unsigned char* __restrict__ S,
               const float* __restrict__ EPS, double* __restrict__ accum,
               int M, int N, int K, int MT) {
    __shared__ __align__(16) unsigned char lds[2][2][128 * 64];

    const int tid  = threadIdx.x;
    const int lane = tid & 63;
    const int wave = tid >> 6;      // 0..3
    const int wr   = wave >> 1;     // 0..1
    const int wc   = wave & 1;      // 0..1

    // XCD-aware bijective chunked decode (gridDim.x % 8 == 0 here)
    const int nwg  = gridDim.x;
    const int cpx  = nwg >> 3;
    const int work = (blockIdx.x & 7) * cpx + (blockIdx.x >> 3);
    const int ntile = work / MT;
    const int mtile = work - ntile * MT;
    const int m0 = mtile * 128;
    const int n0 = ntile * 128;

    const int nk = K >> 6;          // # K-steps of 64 bytes

    const int srow = tid >> 2;      // 0..63
    const int skb  = tid & 3;       // 16B slot 0..3

    auto stage = [&](int buf, int kt) {
        const size_t kcol = (size_t)kt * 64;
#pragma unroll
        for (int mat = 0; mat < 2; ++mat) {
            const unsigned char* G = mat ? BT : A;
            const int base0 = mat ? n0 : m0;
#pragma unroll
            for (int j = 0; j < 2; ++j) {
                int row = j * 64 + srow;
                int sg  = skb ^ ((row >> 1) & 3);   // inverse-swizzled source
                gload_lds16(G + (size_t)(base0 + row) * K + kcol + (size_t)sg * 16,
                            &lds[buf][mat][row * 64 + skb * 16]);  // linear dest
            }
        }
    };

    const int g32 = (lane >> 5);       // k-chunk group (0..1)
    const int l31 = lane & 31;
    auto rdfrag = [&](const unsigned char* base, int row) -> i32x8 {
        const unsigned char* rp = base + row * 64;
        int r3 = (row >> 1) & 3;       // bank-bijective swizzle
        int s0 = g32 * 2;
        i32x4 lo = *(const i32x4*)(rp + (((s0    ) ^ r3) << 4));
        i32x4 hi = *(const i32x4*)(rp + (((s0 + 1) ^ r3) << 4));
        return __builtin_shufflevector(lo, hi, 0, 1, 2, 3, 4, 5, 6, 7);
    };

    f32x16 acc[2][2] = {};

    stage(0, 0);
    __syncthreads();
    int cur = 0;
    for (int t = 0; t < nk; ++t) {
        if (t + 1 < nk) stage(cur ^ 1, t + 1);
        i32x8 a0 = rdfrag(lds[cur][0], wr * 64 +  0 + l31);
        i32x8 a1 = rdfrag(lds[cur][0], wr * 64 + 32 + l31);
        i32x8 b0 = rdfrag(lds[cur][1], wc * 64 +  0 + l31);
        i32x8 b1 = rdfrag(lds[cur][1], wc * 64 + 32 + l31);
        acc[0][0] = __builtin_amdgcn_mfma_scale_f32_32x32x64_f8f6f4(
            a0, b0, acc[0][0], 0, 0, 0, SCALE_A_DW, 0, SCALE_B_DW);
        acc[0][1] = __builtin_amdgcn_mfma_scale_f32_32x32x64_f8f6f4(
            a0, b1, acc[0][1], 0, 0, 0, SCALE_A_DW, 0, SCALE_B_DW);
        acc[1][0] = __builtin_amdgcn_mfma_scale_f32_32x32x64_f8f6f4(
            a1, b0, acc[1][0], 0, 0, 0, SCALE_A_DW, 0, SCALE_B_DW);
        acc[1][1] = __builtin_amdgcn_mfma_scale_f32_32x32x64_f8f6f4(
            a1, b1, acc[1][1], 0, 0, 0, SCALE_A_DW, 0, SCALE_B_DW);
        __syncthreads();
        cur ^= 1;
    }

    // epilogue: 32x32 C/D map col=lane&31, row=(reg&3)+8*(reg>>2)+4*(lane>>5)
    float lsum = 0.f;
#pragma unroll
    for (int mi = 0; mi < 2; ++mi) {
#pragma unroll
        for (int nj = 0; nj < 2; ++nj) {
            int colg = n0 + wc * 64 + nj * 32 + l31;
            float bv;
            if (EPI == 2)
                bv = (colg & 1) ? bias[1024 + (colg >> 1)] : bias[colg >> 1];
            else
                bv = bias[colg];
#pragma unroll
            for (int reg = 0; reg < 16; ++reg) {
                int row = m0 + wr * 64 + mi * 32 +
                          (reg & 3) + 8 * (reg >> 2) + 4 * g32;
                float v = acc[mi][nj][reg] + bv;
                if (EPI == 0) {
                    float ge = 0.5f * v * (1.f + erff(v * 0.70710678118f));
                    ((unsigned char*)Cout)[(size_t)row * N + colg] =
                        f2fp8(ge * ASCALE);
                } else if (EPI == 2) {
                    float other = __shfl_xor(v, 1);
                    if ((lane & 1) == 0) {
                        float mu = v, lv = other;
                        float el = expf(lv);
                        size_t zi = (size_t)row * 1024 + (colg >> 1);
                        float zz = mu + sqrtf(el) * EPS[zi];
                        ((unsigned char*)Cout)[zi] = f2fp8(zz * ASCALE);
                        lsum += 1.f + lv - mu * mu - el;
                    }
                } else {
                    unsigned int sb = S[(size_t)row * N + colg];
                    float sv = __builtin_amdgcn_cvt_f32_fp8(sb, 0) * (1.0f / ASCALE);
                    float d = v - sv;
                    lsum += d * d;
                }
            }
        }
    }

    if (EPI == 2 || EPI == 3) {
        __shared__ float red[4];
        float v = lsum;
#pragma unroll
        for (int o = 32; o > 0; o >>= 1) v += __shfl_down(v, o);
        if (lane == 0) red[wave] = v;
        __syncthreads();
        if (tid == 0) {
            double t = (double)red[0] + (double)red[1] +
                       (double)red[2] + (double)red[3];
            atomicAdd(accum + (EPI == 2 ? 1 : 0), t);
        }
    }
}

// ---------------------------------------------------------------------------
__global__ void finalize_kernel(const double* __restrict__ acc,
                                float* __restrict__ out) {
    if (threadIdx.x == 0)
        out[0] = (float)(acc[0] * (1.0 / (16384.0 * 4096.0)) - 0.0005 * acc[1]);
}

// ---------------------------------------------------------------------------
extern "C" void kernel_launch(void* const* d_in, const int* in_sizes, int n_in,
                              void* d_out, int out_size, void* d_ws, size_t ws_size,
                              hipStream_t stream) {
    const float* hidden = (const float*)d_in[0];
    const float* memory = (const float*)d_in[1];
    const int*   idx    = (const int*)d_in[2];
    const float* eps    = (const float*)d_in[3];
    const float* W1     = (const float*)d_in[4];
    const float* b1     = (const float*)d_in[5];
    const float* W2     = (const float*)d_in[6];
    const float* b2     = (const float*)d_in[7];
    const float* Wd1    = (const float*)d_in[8];
    const float* bd1    = (const float*)d_in[9];
    const float* Wd2    = (const float*)d_in[10];
    const float* bd2    = (const float*)d_in[11];

    char* ws = (char*)d_ws;
    double* acc            = (double*)ws;                            // 256 B
    unsigned char* s8      = (unsigned char*)(ws + 256);             // 67 MB
    unsigned char* h8      = s8   + (size_t)16384 * 4096;            // 33.6 MB
    unsigned char* z8      = h8   + (size_t)16384 * 2048;            // 16.8 MB
    unsigned char* hd8     = z8   + (size_t)16384 * 1024;            // 33.6 MB
    unsigned char* W1T     = hd8  + (size_t)16384 * 2048;
    unsigned char* W2T     = W1T  + (size_t)2048 * 4096;
    unsigned char* Wd1T    = W2T  + (size_t)2048 * 2048;
    unsigned char* Wd2T    = Wd1T + (size_t)2048 * 1024;

    // one fused prep launch: gather + 4 transposes + acc zeroing
    prep_kernel<<<38912, 256, 0, stream>>>(hidden, memory, idx, s8,
                                           W1, W1T, W2, W2T,
                                           Wd1, Wd1T, Wd2, Wd2T, acc);

    // h = gelu(samples @ W1 + b1)          M=16384 N=2048 K=4096
    gemm128f8<0><<<2048, 256, 0, stream>>>(s8, W1T, b1, h8, nullptr, nullptr,
                                           nullptr, 16384, 2048, 4096, 128);
    // enc (interleaved) -> fused reparam: z fp8 + KL partials   K=2048
    gemm128f8<2><<<2048, 256, 0, stream>>>(h8, W2T, b2, z8, nullptr, eps,
                                           acc, 16384, 2048, 2048, 128);
    // hd = gelu(z @ Wd1 + bd1)             K=1024
    gemm128f8<0><<<2048, 256, 0, stream>>>(z8, Wd1T, bd1, hd8, nullptr, nullptr,
                                           nullptr, 16384, 2048, 1024, 128);
    // rec = hd @ Wd2 + bd2 ; fused recon MSE vs deq(s8)   N=4096 K=2048
    gemm128f8<3><<<4096, 256, 0, stream>>>(hd8, Wd2T, bd2, nullptr, s8,
                                           nullptr, acc, 16384, 4096, 2048, 128);

    finalize_kernel<<<1, 64, 0, stream>>>(acc, (float*)d_out);
}